// Round 5
// baseline (1202.135 us; speedup 1.0000x reference)
//
#include <hip/hip_runtime.h>
#include <hip/hip_bf16.h>

// Problem dims
#define PP 512
#define QQ 64
#define BB 16
#define EE 256
#define HH 256
#define OO 256

typedef _Float16 half2_t __attribute__((ext_vector_type(2)));
typedef _Float16 f16x8 __attribute__((ext_vector_type(8)));
typedef float f32x4 __attribute__((ext_vector_type(4)));

__device__ __forceinline__ void unpack8h(const uint4 r, float* v) {
    const _Float16* s = (const _Float16*)&r;
#pragma unroll
    for (int i = 0; i < 8; i++) v[i] = (float)s[i];
}
__device__ __forceinline__ float fast_tanh(float x) {
    x = fminf(fmaxf(x, -15.f), 15.f);
    float e = __expf(2.f * x);
    return (e - 1.f) * __frcp_rn(e + 1.f);
}
__device__ __forceinline__ float fast_sigmoid(float x) {
    x = fminf(fmaxf(x, -30.f), 30.f);
    return __frcp_rn(1.f + __expf(-x));
}

// ---------------------------------------------------------------------------
// Generic tiled GEMM: C[m,n] = epilogue( sum_k A[m,k] * B[n,k] )
// Tile 128x128, K-chunk 16, 256 threads, 8x8 micro-tile, fp32 accumulate.
// Output fp16. B (weight) is fp32, row n = B[n, 0:K].
// AMODE: 0 = A fp32 (row stride K)
//        2 = A concat: k<256 -> Af32 (fp32, row stride 256), k>=256 -> Ah (f16, row stride 256)
//        3 = A f16 (row stride K)
// EPI:   0 = none
//        1 = + bias[n] (fp32)
//        2 = sigmoid(acc) * gateC[m*256+n] (f16)   [only used with N=256]
// ---------------------------------------------------------------------------
template <int AMODE, int EPI>
__global__ __launch_bounds__(256) void gemm_k(
    const float* __restrict__ Af32,
    const _Float16* __restrict__ Ah,
    const float* __restrict__ Bw,
    const float* __restrict__ bias,
    const _Float16* __restrict__ gateC,
    _Float16* __restrict__ Cout, int M, int N, int K)
{
    __shared__ float As[16][128];
    __shared__ float Bs[16][128];
    const int tid = threadIdx.x;
    const int bm = blockIdx.x, bn = blockIdx.y;
    const int ra = tid >> 1;          // 0..127 : row within tile for staging
    const int ka = (tid & 1) * 8;     // 0 or 8 : k-offset within chunk
    const int tm = (tid >> 4) * 8;    // micro-tile row base
    const int tn = (tid & 15) * 8;    // micro-tile col base

    float acc[8][8];
#pragma unroll
    for (int i = 0; i < 8; i++)
#pragma unroll
        for (int j = 0; j < 8; j++) acc[i][j] = 0.f;

    const long arow = (long)bm * 128 + ra;
    const long brow = (long)bn * 128 + ra;

    for (int k0 = 0; k0 < K; k0 += 16) {
        float av[8], bv[8];
        const int kk = k0 + ka;
        if (AMODE == 0) {
            const float* p = Af32 + arow * K + kk;
            float4 r0 = *(const float4*)(p);
            float4 r1 = *(const float4*)(p + 4);
            av[0] = r0.x; av[1] = r0.y; av[2] = r0.z; av[3] = r0.w;
            av[4] = r1.x; av[5] = r1.y; av[6] = r1.z; av[7] = r1.w;
        } else if (AMODE == 3) {
            uint4 r = *(const uint4*)(Ah + arow * K + kk);
            unpack8h(r, av);
        } else { // AMODE == 2
            if (kk < 256) {
                const float* p = Af32 + arow * 256 + kk;
                float4 r0 = *(const float4*)(p);
                float4 r1 = *(const float4*)(p + 4);
                av[0] = r0.x; av[1] = r0.y; av[2] = r0.z; av[3] = r0.w;
                av[4] = r1.x; av[5] = r1.y; av[6] = r1.z; av[7] = r1.w;
            } else {
                uint4 r = *(const uint4*)(Ah + arow * 256 + (kk - 256));
                unpack8h(r, av);
            }
        }
        {
            const float* p = Bw + brow * K + kk;
            float4 r0 = *(const float4*)(p);
            float4 r1 = *(const float4*)(p + 4);
            bv[0] = r0.x; bv[1] = r0.y; bv[2] = r0.z; bv[3] = r0.w;
            bv[4] = r1.x; bv[5] = r1.y; bv[6] = r1.z; bv[7] = r1.w;
        }
        __syncthreads();
#pragma unroll
        for (int i = 0; i < 8; i++) { As[ka + i][ra] = av[i]; Bs[ka + i][ra] = bv[i]; }
        __syncthreads();
#pragma unroll
        for (int k = 0; k < 16; k++) {
            float a[8], b[8];
            *(float4*)&a[0] = *(const float4*)&As[k][tm];
            *(float4*)&a[4] = *(const float4*)&As[k][tm + 4];
            *(float4*)&b[0] = *(const float4*)&Bs[k][tn];
            *(float4*)&b[4] = *(const float4*)&Bs[k][tn + 4];
#pragma unroll
            for (int i = 0; i < 8; i++)
#pragma unroll
                for (int j = 0; j < 8; j++)
                    acc[i][j] = fmaf(a[i], b[j], acc[i][j]);
        }
    }

#pragma unroll
    for (int i = 0; i < 8; i++) {
        const long m = (long)bm * 128 + tm + i;
#pragma unroll
        for (int j = 0; j < 8; j++) {
            const int n = bn * 128 + tn + j;
            float v = acc[i][j];
            if (EPI == 1) v += bias[n];
            if (EPI == 2) v = fast_sigmoid(v) * (float)gateC[m * 256 + n];
            Cout[m * (long)N + n] = (_Float16)v;
        }
    }
}

// ---------------------------------------------------------------------------
// Fused attention: per block = one (p,b) pair (m = p*16+b).
// ---------------------------------------------------------------------------
__global__ __launch_bounds__(256) void attn_k(
    const float* __restrict__ question,  // (Q,B,E) fp32
    const float* __restrict__ vvec,      // (H,) fp32
    const _Float16* __restrict__ Wp,     // (P*B, H) f16
    const _Float16* __restrict__ Wq,     // (Q*B, H) f16
    _Float16* __restrict__ Cc)           // (P*B, E) f16 out
{
    __shared__ float sc[QQ];
    __shared__ float aw[QQ];
    const int tid = threadIdx.x;
    const int blk = blockIdx.x;   // m = p*16 + b
    const int b = blk & 15;
    const int wave = tid >> 6, lane = tid & 63;

    float wp0[4], vv[4];
#pragma unroll
    for (int j = 0; j < 4; j++) {
        wp0[j] = (float)Wp[(long)blk * 256 + lane + 64 * j];
        vv[j] = vvec[lane + 64 * j];
    }
#pragma unroll 2
    for (int qi = 0; qi < 16; qi++) {
        const int q = wave * 16 + qi;
        const _Float16* wqp = Wq + (long)(q * 16 + b) * 256;
        float s = 0.f;
#pragma unroll
        for (int j = 0; j < 4; j++) {
            float x = (float)wqp[lane + 64 * j] + wp0[j];
            s += fast_tanh(x) * vv[j];
        }
#pragma unroll
        for (int off = 32; off; off >>= 1) s += __shfl_xor(s, off, 64);
        if (lane == 0) sc[q] = s;
    }
    __syncthreads();
    if (tid < 64) {
        float s = sc[tid];
        float mx = s;
#pragma unroll
        for (int off = 32; off; off >>= 1) mx = fmaxf(mx, __shfl_xor(mx, off, 64));
        float e = __expf(s - mx);
        float sum = e;
#pragma unroll
        for (int off = 32; off; off >>= 1) sum += __shfl_xor(sum, off, 64);
        aw[tid] = e * __frcp_rn(sum);
    }
    __syncthreads();
    float acc = 0.f;
#pragma unroll 4
    for (int q = 0; q < QQ; q++) {
        acc = fmaf(aw[q], question[(long)(q * 16 + b) * 256 + tid], acc);
    }
    Cc[(long)blk * 256 + tid] = (_Float16)acc;
}

// ---------------------------------------------------------------------------
// GRU scan, v7: single-barrier MFMA scan. 16 blocks (one per batch),
// 512 threads (8 waves, 2/SIMD, 256 unified regs via waves_per_eu(2,2)).
//
// v6 post-mortem: replacing the v_dot2 matvec (~2000 VALU cyc) with MFMA
// (~470 cyc) only cut the step from ~3300 to ~2900 cyc -> ~2400 cyc/step is
// the 2-phase SKELETON (2 barriers, gh LDS round-trip, phase hand-off), not
// the matvec. v7 collapses the skeleton using the fact that wave w's six
// accumulators hold ALL THREE gate pre-activations for the SAME e-range
// [32w, 32w+32): lanes 0-15 (which own C row 0: col=lane&15, reg 0 --
// layout verified by v6 passing) apply the gate nonlinearities in-register
// and write h (f16) straight to the double-buffered broadcast buffer.
// No ghlds, no second phase, ONE barrier and ONE LDS round-trip per step.
//
// Per step per wave: 8 ds_read_b128 (broadcast within 16-lane groups,
// conflict-free) + 48 MFMA; lanes 0-15: 2 gate-triples in-register,
// 2 ds_write_b16, 2 global stores. Double-buffer race check: writes go to
// hbuf[cur^1] while reads hit hbuf[cur]; the single barrier orders
// write(t) -> read(t+1) and read(t) -> write(t+1). gi prefetch issued at
// step top, consumed next step (the t=511 prefetch reads one row past gi --
// inside the 16 MiB workspace, value unused).
// ---------------------------------------------------------------------------
__global__ __launch_bounds__(512)
__attribute__((amdgpu_waves_per_eu(2, 2)))
void gru_k(
    const float* __restrict__ whh,    // (768,256) fp32
    const float* __restrict__ bhh,    // (768,) fp32
    const _Float16* __restrict__ gi,  // (P*B, 768) f16 (b_ih folded in)
    float* __restrict__ out)          // (P,B,O) fp32
{
    __shared__ __align__(16) _Float16 hbuf[2][256];   // h broadcast, double-buffered
    const int tid = threadIdx.x;
    const int w = tid >> 6;        // wave 0..7
    const int lane = tid & 63;
    const int b = blockIdx.x;      // batch

    // ---- stage weights into per-wave B-fragments (AGPR-resident) ----
    // B[k][n] = w_hh[nbase+n][k]; lane holds n = lane&15,
    // k = kk*32 + 8*(lane>>4) + [0..8)  (same k-order as A packing).
    f16x8 bf[3][2][8];
#pragma unroll
    for (int g = 0; g < 3; g++)
#pragma unroll
        for (int c = 0; c < 2; c++) {
            const int n0 = g * 256 + 32 * w + 16 * c + (lane & 15);
            const float* wp = whh + (long)n0 * 256 + 8 * (lane >> 4);
#pragma unroll
            for (int kk = 0; kk < 8; kk++) {
                float4 r0 = *(const float4*)(wp + kk * 32);
                float4 r1 = *(const float4*)(wp + kk * 32 + 4);
                f16x8 t;
                t[0] = (_Float16)r0.x; t[1] = (_Float16)r0.y;
                t[2] = (_Float16)r0.z; t[3] = (_Float16)r0.w;
                t[4] = (_Float16)r1.x; t[5] = (_Float16)r1.y;
                t[6] = (_Float16)r1.z; t[7] = (_Float16)r1.w;
                bf[g][c][kk] = t;
            }
        }

    // ---- epilogue-owner state: lanes 0-15 own e0 = 32w+lane, e1 = e0+16 ----
    const bool owner = (lane < 16);
    const int e0 = 32 * w + (lane & 15);
    float h0 = 0.f, h1 = 0.f;
    float br0 = 0.f, bz0 = 0.f, bn0 = 0.f, br1 = 0.f, bz1 = 0.f, bn1 = 0.f;
    float gr0 = 0.f, gz0 = 0.f, gn0 = 0.f, gr1 = 0.f, gz1 = 0.f, gn1 = 0.f;
    const _Float16* gip = gi + (long)b * 768 + e0;   // current step's row
    float* outp = out + (long)b * 256 + e0;
    if (owner) {
        br0 = bhh[e0];      bz0 = bhh[e0 + 256]; bn0 = bhh[e0 + 512];
        br1 = bhh[e0 + 16]; bz1 = bhh[e0 + 272]; bn1 = bhh[e0 + 528];
        gr0 = (float)gip[0];  gz0 = (float)gip[256]; gn0 = (float)gip[512];
        gr1 = (float)gip[16]; gz1 = (float)gip[272]; gn1 = (float)gip[528];
    }
    if (tid < 256) hbuf[0][tid] = (_Float16)0.f;
    __syncthreads();

    // A-frag source: all lanes in a 16-lane group read the SAME 16B of h
    // (broadcast); non-row-0 lanes mask their copy to zero.
    const unsigned msk = ((lane & 15) == 0) ? 0xFFFFFFFFu : 0u;

    int cur = 0;
    for (int t = 0; t < PP; t++) {
        // Prefetch next step's gi first (HBM latency hides under the MFMAs).
        float pgr0 = 0.f, pgz0 = 0.f, pgn0 = 0.f, pgr1 = 0.f, pgz1 = 0.f, pgn1 = 0.f;
        if (owner) {
            const _Float16* gq = gip + 16 * 768;
            pgr0 = (float)gq[0];  pgz0 = (float)gq[256]; pgn0 = (float)gq[512];
            pgr1 = (float)gq[16]; pgz1 = (float)gq[272]; pgn1 = (float)gq[528];
        }

        // ---- matvec: 48 MFMA per wave, 6 independent 8-deep chains ----
        const _Float16* hb = hbuf[cur] + 8 * (lane >> 4);
        f32x4 a00 = {0.f, 0.f, 0.f, 0.f}, a01 = {0.f, 0.f, 0.f, 0.f};
        f32x4 a10 = {0.f, 0.f, 0.f, 0.f}, a11 = {0.f, 0.f, 0.f, 0.f};
        f32x4 a20 = {0.f, 0.f, 0.f, 0.f}, a21 = {0.f, 0.f, 0.f, 0.f};
#pragma unroll
        for (int kk = 0; kk < 8; kk++) {
            uint4 ra = *(const uint4*)(hb + kk * 32);
            ra.x &= msk; ra.y &= msk; ra.z &= msk; ra.w &= msk;
            f16x8 a = __builtin_bit_cast(f16x8, ra);
            a00 = __builtin_amdgcn_mfma_f32_16x16x32_f16(a, bf[0][0][kk], a00, 0, 0, 0);
            a01 = __builtin_amdgcn_mfma_f32_16x16x32_f16(a, bf[0][1][kk], a01, 0, 0, 0);
            a10 = __builtin_amdgcn_mfma_f32_16x16x32_f16(a, bf[1][0][kk], a10, 0, 0, 0);
            a11 = __builtin_amdgcn_mfma_f32_16x16x32_f16(a, bf[1][1][kk], a11, 0, 0, 0);
            a20 = __builtin_amdgcn_mfma_f32_16x16x32_f16(a, bf[2][0][kk], a20, 0, 0, 0);
            a21 = __builtin_amdgcn_mfma_f32_16x16x32_f16(a, bf[2][1][kk], a21, 0, 0, 0);
        }

        // ---- gates in-register (lanes 0-15): row 0 = reg 0, col = lane&15 ----
        if (owner) {
            float r0 = fast_sigmoid(gr0 + a00[0] + br0);
            float z0 = fast_sigmoid(gz0 + a10[0] + bz0);
            float n0 = fast_tanh(fmaf(r0, a20[0] + bn0, gn0));
            h0 = (1.f - z0) * n0 + z0 * h0;
            float r1 = fast_sigmoid(gr1 + a01[0] + br1);
            float z1 = fast_sigmoid(gz1 + a11[0] + bz1);
            float n1 = fast_tanh(fmaf(r1, a21[0] + bn1, gn1));
            h1 = (1.f - z1) * n1 + z1 * h1;
            outp[0] = h0;
            outp[16] = h1;
            hbuf[cur ^ 1][e0] = (_Float16)h0;
            hbuf[cur ^ 1][e0 + 16] = (_Float16)h1;
            gr0 = pgr0; gz0 = pgz0; gn0 = pgn0;
            gr1 = pgr1; gz1 = pgz1; gn1 = pgn1;
            gip += 16 * 768;
            outp += 16 * 256;
        }
        __syncthreads();
        cur ^= 1;
    }
}

// ---------------------------------------------------------------------------
extern "C" void kernel_launch(void* const* d_in, const int* in_sizes, int n_in,
                              void* d_out, int out_size, void* d_ws, size_t ws_size,
                              hipStream_t stream)
{
    const float* passage  = (const float*)d_in[0];   // (512,16,256) fp32
    const float* question = (const float*)d_in[1];   // (64,16,256) fp32
    const float* Wuq      = (const float*)d_in[2];   // (256,256) fp32
    const float* Wup      = (const float*)d_in[3];   // (256,256) fp32
    const float* vvec     = (const float*)d_in[4];   // (1,256) fp32
    const float* Wg       = (const float*)d_in[5];   // (512,512) fp32
    const float* w_ih     = (const float*)d_in[6];   // (768,256) fp32
    const float* w_hh     = (const float*)d_in[7];   // (768,256) fp32
    const float* b_ih     = (const float*)d_in[8];   // (768,) fp32
    const float* b_hh     = (const float*)d_in[9];   // (768,) fp32

    // Workspace layout (all fp16) — total footprint exactly 16 MiB.
    //   [0,      12.0MiB) : gi (8192x768)  — written LAST; overlaps Wq/Wp/c,
    //                        which are all dead by the time gi is produced.
    //       [0,     0.5MiB) : Wq (1024x256)   dead after attn
    //       [0.5,   4.5MiB) : Wp (8192x256)   dead after attn
    //       [4.5,   8.5MiB) : c  (8192x256)   dead after gate GEMM
    //   [12MiB, 16MiB)     : cg (8192x256)    alive until gi GEMM done
    char* ws = (char*)d_ws;
    _Float16* gi_ws = (_Float16*)(ws);
    _Float16* Wq_ws = (_Float16*)(ws);
    _Float16* Wp_ws = (_Float16*)(ws + (512u << 10));
    _Float16* c_ws  = (_Float16*)(ws + (4608u << 10));
    _Float16* cg_ws = (_Float16*)(ws + (12288u << 10));

    // 1) Wq = question @ Wuq^T   (1024 x 256, K=256)
    gemm_k<0, 0><<<dim3(8, 2), 256, 0, stream>>>(question, nullptr, Wuq, nullptr, nullptr,
                                                 Wq_ws, 1024, 256, 256);
    // 2) Wp = passage @ Wup^T    (8192 x 256, K=256)
    gemm_k<0, 0><<<dim3(64, 2), 256, 0, stream>>>(passage, nullptr, Wup, nullptr, nullptr,
                                                  Wp_ws, 8192, 256, 256);
    // 3) attention -> c (8192 x 256)
    attn_k<<<8192, 256, 0, stream>>>(question, vvec, Wp_ws, Wq_ws, c_ws);
    // 4) cg = sigmoid([passage,c] @ Wg[256:512]^T) * c   (8192 x 256, K=512)
    gemm_k<2, 2><<<dim3(64, 2), 256, 0, stream>>>(passage, c_ws, Wg + 256 * 512, nullptr, c_ws,
                                                  cg_ws, 8192, 256, 512);
    // 5) gi = cg @ w_ih^T + b_ih   (8192 x 768, K=256)
    gemm_k<3, 1><<<dim3(64, 6), 256, 0, stream>>>(nullptr, cg_ws, w_ih, b_ih, nullptr,
                                                  gi_ws, 8192, 768, 256);
    // 6) GRU scan -> out (fp32)
    gru_k<<<16, 512, 0, stream>>>(w_hh, b_hh, gi_ws, (float*)d_out);
}

// Round 6
// 900.293 us; speedup vs baseline: 1.3353x; 1.3353x over previous
//
#include <hip/hip_runtime.h>
#include <hip/hip_bf16.h>

// Problem dims
#define PP 512
#define QQ 64
#define BB 16
#define EE 256
#define HH 256
#define OO 256

typedef _Float16 half2_t __attribute__((ext_vector_type(2)));
typedef _Float16 f16x8 __attribute__((ext_vector_type(8)));
typedef float f32x4 __attribute__((ext_vector_type(4)));

__device__ __forceinline__ float fast_tanh(float x) {
    x = fminf(fmaxf(x, -15.f), 15.f);
    float e = __expf(2.f * x);
    return (e - 1.f) * __frcp_rn(e + 1.f);
}
__device__ __forceinline__ float fast_sigmoid(float x) {
    x = fminf(fmaxf(x, -30.f), 30.f);
    return __frcp_rn(1.f + __expf(-x));
}
__device__ __forceinline__ f16x8 cvt8(const float* __restrict__ p) {
    float4 r0 = *(const float4*)(p);
    float4 r1 = *(const float4*)(p + 4);
    f16x8 t;
    t[0] = (_Float16)r0.x; t[1] = (_Float16)r0.y;
    t[2] = (_Float16)r0.z; t[3] = (_Float16)r0.w;
    t[4] = (_Float16)r1.x; t[5] = (_Float16)r1.y;
    t[6] = (_Float16)r1.z; t[7] = (_Float16)r1.w;
    return t;
}

// ---------------------------------------------------------------------------
// MFMA GEMM with register-resident B: C[m,n] = epi( sum_k A[m,k]*B[n,k] ).
// Shapes here are weight-skinny (N<=768, K<=512), so each block parks its
// whole B-strip as MFMA fragments: bf[BN/16][K/32] f16x8 = 128 regs.
// Only MFMA reads bf, so AGPR placement (which the allocator will choose)
// costs nothing -- the round-0..3 AGPR tax inverted into an asset.
// No LDS, no barriers. 256 threads = 4 waves; BM=64, wave w owns rows
// [bm*64+16w, +16). Per k-step: 1 A-frag (global, cvt if fp32) + NT MFMAs.
// Fragment mappings hardware-verified by the v6 GRU kernel:
//   A: m=lane&15, k=8*(lane>>4)+j ; B: n=lane&15, same k order ;
//   C/D: col=lane&15, row=(lane>>4)*4+reg.
// AMODE: 0 = A fp32 (row stride K)
//        2 = A concat (K=512): k<256 -> Af32 (stride 256), k>=256 -> Ah f16
//        3 = A f16 (row stride K)
// EPI:   0 none | 1 +bias[n] | 2 sigmoid(acc)*gateC[m*256+n]
// ---------------------------------------------------------------------------
template <int AMODE, int EPI, int BN, int KK>
__global__ __launch_bounds__(256)
__attribute__((amdgpu_waves_per_eu(2, 2)))
void gemm_mfma(
    const float* __restrict__ Af32,
    const _Float16* __restrict__ Ah,
    const float* __restrict__ Bw,
    const float* __restrict__ bias,
    const _Float16* __restrict__ gateC,
    _Float16* __restrict__ Cout, int M, int N)
{
    constexpr int NT = BN / 16;   // n-tiles per block (4 or 2)
    constexpr int KS = KK / 32;   // k-steps (8 or 16)
    const int tid = threadIdx.x;
    const int w = tid >> 6;
    const int lane = tid & 63;
    const int ln = lane & 15;     // fragment n / m index
    const int lk = lane >> 4;     // fragment k-group
    const int bm = blockIdx.x, bn = blockIdx.y;

    // ---- park B-strip in fragments (AGPR-resident across the k-loop) ----
    f16x8 bf[NT][KS];
#pragma unroll
    for (int c = 0; c < NT; c++) {
        const float* wp = Bw + (long)(bn * BN + c * 16 + ln) * KK + 8 * lk;
#pragma unroll
        for (int kk = 0; kk < KS; kk++) bf[c][kk] = cvt8(wp + kk * 32);
    }

    const long arow = (long)bm * 64 + w * 16 + ln;
    f32x4 acc[NT];
#pragma unroll
    for (int c = 0; c < NT; c++) acc[c] = (f32x4){0.f, 0.f, 0.f, 0.f};

#pragma unroll
    for (int kk = 0; kk < KS; kk++) {
        f16x8 a;
        if (AMODE == 0) {
            a = cvt8(Af32 + arow * KK + kk * 32 + 8 * lk);
        } else if (AMODE == 3) {
            a = *(const f16x8*)(Ah + arow * KK + kk * 32 + 8 * lk);
        } else {  // AMODE == 2: KK=512, halves resolve at compile time per kk
            if (kk < KS / 2)
                a = cvt8(Af32 + arow * 256 + kk * 32 + 8 * lk);
            else
                a = *(const f16x8*)(Ah + arow * 256 + (kk - KS / 2) * 32 + 8 * lk);
        }
#pragma unroll
        for (int c = 0; c < NT; c++)
            acc[c] = __builtin_amdgcn_mfma_f32_16x16x32_f16(a, bf[c][kk], acc[c], 0, 0, 0);
    }

    // ---- epilogue: C row = lk*4 + i, col = ln ----
#pragma unroll
    for (int c = 0; c < NT; c++) {
        const int n = bn * BN + c * 16 + ln;
        const float bi = (EPI == 1) ? bias[n] : 0.f;
#pragma unroll
        for (int i = 0; i < 4; i++) {
            const long m = (long)bm * 64 + w * 16 + lk * 4 + i;
            float v = acc[c][i];
            if (EPI == 1) v += bi;
            if (EPI == 2) v = fast_sigmoid(v) * (float)gateC[m * 256 + n];
            Cout[m * (long)N + n] = (_Float16)v;
        }
    }
}

// ---------------------------------------------------------------------------
// Fused attention: per block = one (p,b) pair (m = p*16+b).
// ---------------------------------------------------------------------------
__global__ __launch_bounds__(256) void attn_k(
    const float* __restrict__ question,  // (Q,B,E) fp32
    const float* __restrict__ vvec,      // (H,) fp32
    const _Float16* __restrict__ Wp,     // (P*B, H) f16
    const _Float16* __restrict__ Wq,     // (Q*B, H) f16
    _Float16* __restrict__ Cc)           // (P*B, E) f16 out
{
    __shared__ float sc[QQ];
    __shared__ float aw[QQ];
    const int tid = threadIdx.x;
    const int blk = blockIdx.x;   // m = p*16 + b
    const int b = blk & 15;
    const int wave = tid >> 6, lane = tid & 63;

    float wp0[4], vv[4];
#pragma unroll
    for (int j = 0; j < 4; j++) {
        wp0[j] = (float)Wp[(long)blk * 256 + lane + 64 * j];
        vv[j] = vvec[lane + 64 * j];
    }
#pragma unroll 2
    for (int qi = 0; qi < 16; qi++) {
        const int q = wave * 16 + qi;
        const _Float16* wqp = Wq + (long)(q * 16 + b) * 256;
        float s = 0.f;
#pragma unroll
        for (int j = 0; j < 4; j++) {
            float x = (float)wqp[lane + 64 * j] + wp0[j];
            s += fast_tanh(x) * vv[j];
        }
#pragma unroll
        for (int off = 32; off; off >>= 1) s += __shfl_xor(s, off, 64);
        if (lane == 0) sc[q] = s;
    }
    __syncthreads();
    if (tid < 64) {
        float s = sc[tid];
        float mx = s;
#pragma unroll
        for (int off = 32; off; off >>= 1) mx = fmaxf(mx, __shfl_xor(mx, off, 64));
        float e = __expf(s - mx);
        float sum = e;
#pragma unroll
        for (int off = 32; off; off >>= 1) sum += __shfl_xor(sum, off, 64);
        aw[tid] = e * __frcp_rn(sum);
    }
    __syncthreads();
    float acc = 0.f;
#pragma unroll 4
    for (int q = 0; q < QQ; q++) {
        acc = fmaf(aw[q], question[(long)(q * 16 + b) * 256 + tid], acc);
    }
    Cc[(long)blk * 256 + tid] = (_Float16)acc;
}

// ---------------------------------------------------------------------------
// GRU scan, v6 (restored -- best measured: 622 us). 16 blocks, 512 threads
// (8 waves, 2/SIMD, 256 unified regs via waves_per_eu(2,2)).
// v7's single-barrier variant REGRESSED to 860 us: fusing the gate epilogue
// into lanes 0-15 of every wave doubled VALU issue (965 -> 1815 cyc/step)
// and put the serial gate chain + store drain in front of the only barrier.
// Keep the 2-phase skeleton: all waves MFMA; threads 0-255 apply gates.
// ---------------------------------------------------------------------------
__global__ __launch_bounds__(512)
__attribute__((amdgpu_waves_per_eu(2, 2)))
void gru_k(
    const float* __restrict__ whh,    // (768,256) fp32
    const float* __restrict__ bhh,    // (768,) fp32
    const _Float16* __restrict__ gi,  // (P*B, 768) f16 (b_ih folded in)
    float* __restrict__ out)          // (P,B,O) fp32
{
    __shared__ __align__(16) _Float16 hlds[256];   // h broadcast (row 0 of A)
    __shared__ float ghlds[3][256];                // gate pre-activations
    const int tid = threadIdx.x;
    const int w = tid >> 6;        // wave 0..7
    const int lane = tid & 63;
    const int b = blockIdx.x;      // batch

    // ---- stage weights into per-wave B-fragments (AGPR-resident) ----
    f16x8 bf[3][2][8];
#pragma unroll
    for (int g = 0; g < 3; g++)
#pragma unroll
        for (int c = 0; c < 2; c++) {
            const int n0 = g * 256 + 32 * w + 16 * c + (lane & 15);
            const float* wp = whh + (long)n0 * 256 + 8 * (lane >> 4);
#pragma unroll
            for (int kk = 0; kk < 8; kk++) bf[g][c][kk] = cvt8(wp + kk * 32);
        }

    // ---- per-thread state for the epilogue owners (threads 0..255) ----
    float h = 0.f, bhr = 0.f, bhz = 0.f, bhn = 0.f;
    _Float16 gr = (_Float16)0.f, gz = (_Float16)0.f, gn = (_Float16)0.f;
    const _Float16* gip = gi;
    float* outp = out;
    if (tid < 256) {
        hlds[tid] = (_Float16)0.f;
        bhr = bhh[tid]; bhz = bhh[tid + 256]; bhn = bhh[tid + 512];
        gip = gi + (long)b * 768 + tid;
        gr = gip[0]; gz = gip[256]; gn = gip[512];
        outp = out + (long)b * 256 + tid;
    }
    __syncthreads();

    // A-frag source: all lanes in a 16-lane group read the SAME 16B of h
    // (broadcast); non-row-0 lanes mask their copy to zero.
    const unsigned msk = ((lane & 15) == 0) ? 0xFFFFFFFFu : 0u;
    const _Float16* hb = hlds + 8 * (lane >> 4);

    for (int t = 0; t < PP; t++) {
        // Prefetch next step's gi (latency hidden under this step's MFMA).
        _Float16 gr2 = (_Float16)0.f, gz2 = (_Float16)0.f, gn2 = (_Float16)0.f;
        if (tid < 256) {
            const _Float16* gq = gip + 16 * 768;
            gr2 = gq[0]; gz2 = gq[256]; gn2 = gq[512];
        }

        // ---- matvec: 48 MFMA per wave ----
        f32x4 a00 = {0.f, 0.f, 0.f, 0.f}, a01 = {0.f, 0.f, 0.f, 0.f};
        f32x4 a10 = {0.f, 0.f, 0.f, 0.f}, a11 = {0.f, 0.f, 0.f, 0.f};
        f32x4 a20 = {0.f, 0.f, 0.f, 0.f}, a21 = {0.f, 0.f, 0.f, 0.f};
#pragma unroll
        for (int kk = 0; kk < 8; kk++) {
            uint4 ra = *(const uint4*)(hb + kk * 32);
            ra.x &= msk; ra.y &= msk; ra.z &= msk; ra.w &= msk;
            f16x8 a = __builtin_bit_cast(f16x8, ra);
            a00 = __builtin_amdgcn_mfma_f32_16x16x32_f16(a, bf[0][0][kk], a00, 0, 0, 0);
            a01 = __builtin_amdgcn_mfma_f32_16x16x32_f16(a, bf[0][1][kk], a01, 0, 0, 0);
            a10 = __builtin_amdgcn_mfma_f32_16x16x32_f16(a, bf[1][0][kk], a10, 0, 0, 0);
            a11 = __builtin_amdgcn_mfma_f32_16x16x32_f16(a, bf[1][1][kk], a11, 0, 0, 0);
            a20 = __builtin_amdgcn_mfma_f32_16x16x32_f16(a, bf[2][0][kk], a20, 0, 0, 0);
            a21 = __builtin_amdgcn_mfma_f32_16x16x32_f16(a, bf[2][1][kk], a21, 0, 0, 0);
        }
        // Row 0 of C lives in lanes 0..15, reg 0 (col = lane&15).
        if (lane < 16) {
            const int e0 = 32 * w + lane;
            ghlds[0][e0] = a00[0]; ghlds[0][e0 + 16] = a01[0];
            ghlds[1][e0] = a10[0]; ghlds[1][e0 + 16] = a11[0];
            ghlds[2][e0] = a20[0]; ghlds[2][e0 + 16] = a21[0];
        }
        __syncthreads();

        // ---- gates: one e-column per thread, spread over all SIMDs ----
        if (tid < 256) {
            float ghr = ghlds[0][tid] + bhr;
            float ghz = ghlds[1][tid] + bhz;
            float ghn = ghlds[2][tid] + bhn;
            float r = fast_sigmoid((float)gr + ghr);
            float z = fast_sigmoid((float)gz + ghz);
            float n = fast_tanh(fmaf(r, ghn, (float)gn));
            h = (1.f - z) * n + z * h;
            *outp = h;
            hlds[tid] = (_Float16)h;
            gr = gr2; gz = gz2; gn = gn2;
            gip += 16 * 768;
            outp += 16 * 256;
        }
        __syncthreads();
    }
}

// ---------------------------------------------------------------------------
extern "C" void kernel_launch(void* const* d_in, const int* in_sizes, int n_in,
                              void* d_out, int out_size, void* d_ws, size_t ws_size,
                              hipStream_t stream)
{
    const float* passage  = (const float*)d_in[0];   // (512,16,256) fp32
    const float* question = (const float*)d_in[1];   // (64,16,256) fp32
    const float* Wuq      = (const float*)d_in[2];   // (256,256) fp32
    const float* Wup      = (const float*)d_in[3];   // (256,256) fp32
    const float* vvec     = (const float*)d_in[4];   // (1,256) fp32
    const float* Wg       = (const float*)d_in[5];   // (512,512) fp32
    const float* w_ih     = (const float*)d_in[6];   // (768,256) fp32
    const float* w_hh     = (const float*)d_in[7];   // (768,256) fp32
    const float* b_ih     = (const float*)d_in[8];   // (768,) fp32
    const float* b_hh     = (const float*)d_in[9];   // (768,) fp32

    // Workspace layout (all fp16) — total footprint exactly 16 MiB.
    //   [0,      12.0MiB) : gi (8192x768)  — written LAST; overlaps Wq/Wp/c,
    //                        which are all dead by the time gi is produced.
    //       [0,     0.5MiB) : Wq (1024x256)   dead after attn
    //       [0.5,   4.5MiB) : Wp (8192x256)   dead after attn
    //       [4.5,   8.5MiB) : c  (8192x256)   dead after gate GEMM
    //   [12MiB, 16MiB)     : cg (8192x256)    alive until gi GEMM done
    char* ws = (char*)d_ws;
    _Float16* gi_ws = (_Float16*)(ws);
    _Float16* Wq_ws = (_Float16*)(ws);
    _Float16* Wp_ws = (_Float16*)(ws + (512u << 10));
    _Float16* c_ws  = (_Float16*)(ws + (4608u << 10));
    _Float16* cg_ws = (_Float16*)(ws + (12288u << 10));

    // 1) Wq = question @ Wuq^T   (1024 x 256, K=256)
    gemm_mfma<0, 0, 64, 256><<<dim3(16, 4), 256, 0, stream>>>(
        question, nullptr, Wuq, nullptr, nullptr, Wq_ws, 1024, 256);
    // 2) Wp = passage @ Wup^T    (8192 x 256, K=256)
    gemm_mfma<0, 0, 64, 256><<<dim3(128, 4), 256, 0, stream>>>(
        passage, nullptr, Wup, nullptr, nullptr, Wp_ws, 8192, 256);
    // 3) attention -> c (8192 x 256)
    attn_k<<<8192, 256, 0, stream>>>(question, vvec, Wp_ws, Wq_ws, c_ws);
    // 4) cg = sigmoid([passage,c] @ Wg[256:512]^T) * c   (8192 x 256, K=512)
    gemm_mfma<2, 2, 32, 512><<<dim3(128, 8), 256, 0, stream>>>(
        passage, c_ws, Wg + 256 * 512, nullptr, c_ws, cg_ws, 8192, 256);
    // 5) gi = cg @ w_ih^T + b_ih   (8192 x 768, K=256)
    gemm_mfma<3, 1, 64, 256><<<dim3(128, 12), 256, 0, stream>>>(
        nullptr, cg_ws, w_ih, b_ih, nullptr, gi_ws, 8192, 768);
    // 6) GRU scan -> out (fp32)
    gru_k<<<16, 512, 0, stream>>>(w_hh, b_hh, gi_ws, (float*)d_out);
}

// Round 7
// 900.064 us; speedup vs baseline: 1.3356x; 1.0003x over previous
//
#include <hip/hip_runtime.h>
#include <hip/hip_bf16.h>

// Problem dims
#define PP 512
#define QQ 64
#define BB 16
#define EE 256
#define HH 256
#define OO 256

typedef _Float16 half2_t __attribute__((ext_vector_type(2)));
typedef _Float16 f16x8 __attribute__((ext_vector_type(8)));
typedef float f32x4 __attribute__((ext_vector_type(4)));

__device__ __forceinline__ float fast_tanh(float x) {
    x = fminf(fmaxf(x, -15.f), 15.f);
    float e = __expf(2.f * x);
    return (e - 1.f) * __frcp_rn(e + 1.f);
}
__device__ __forceinline__ float fast_sigmoid(float x) {
    x = fminf(fmaxf(x, -30.f), 30.f);
    return __frcp_rn(1.f + __expf(-x));
}
__device__ __forceinline__ f16x8 cvt8(const float* __restrict__ p) {
    float4 r0 = *(const float4*)(p);
    float4 r1 = *(const float4*)(p + 4);
    f16x8 t;
    t[0] = (_Float16)r0.x; t[1] = (_Float16)r0.y;
    t[2] = (_Float16)r0.z; t[3] = (_Float16)r0.w;
    t[4] = (_Float16)r1.x; t[5] = (_Float16)r1.y;
    t[6] = (_Float16)r1.z; t[7] = (_Float16)r1.w;
    return t;
}

// LDS-only barrier: orders ds_write -> barrier -> ds_read WITHOUT the
// vmcnt(0)/expcnt(0) drain that __syncthreads() emits. Our step barriers
// only protect LDS traffic; the per-step global ops (gi prefetch loads,
// out stores) must NOT be drained each step -- that drain is the hidden
// serial cost this replaces. sched_barrier(0) pins ordering around the
// inline asm (guide rule #18: hipcc may otherwise hoist ops across it).
__device__ __forceinline__ void block_sync_lds() {
    __builtin_amdgcn_sched_barrier(0);
    asm volatile("s_waitcnt lgkmcnt(0)" ::: "memory");
    __builtin_amdgcn_s_barrier();
    __builtin_amdgcn_sched_barrier(0);
}

// ---------------------------------------------------------------------------
// MFMA GEMM with register-resident B: C[m,n] = epi( sum_k A[m,k]*B[n,k] ).
// Shapes here are weight-skinny (N<=768, K<=512), so each block parks its
// whole B-strip as MFMA fragments: bf[BN/16][K/32] f16x8 = 128 regs.
// Only MFMA reads bf, so AGPR placement (which the allocator will choose)
// costs nothing -- the round-0..3 AGPR tax inverted into an asset.
// No LDS, no barriers. 256 threads = 4 waves; BM=64, wave w owns rows
// [bm*64+16w, +16). Per k-step: 1 A-frag (global, cvt if fp32) + NT MFMAs.
// Fragment mappings hardware-verified by the v6 GRU kernel:
//   A: m=lane&15, k=8*(lane>>4)+j ; B: n=lane&15, same k order ;
//   C/D: col=lane&15, row=(lane>>4)*4+reg.
// AMODE: 0 = A fp32 (row stride K)
//        2 = A concat (K=512): k<256 -> Af32 (stride 256), k>=256 -> Ah f16
//        3 = A f16 (row stride K)
// EPI:   0 none | 1 +bias[n] | 2 sigmoid(acc)*gateC[m*256+n]
// ---------------------------------------------------------------------------
template <int AMODE, int EPI, int BN, int KK>
__global__ __launch_bounds__(256)
__attribute__((amdgpu_waves_per_eu(2, 2)))
void gemm_mfma(
    const float* __restrict__ Af32,
    const _Float16* __restrict__ Ah,
    const float* __restrict__ Bw,
    const float* __restrict__ bias,
    const _Float16* __restrict__ gateC,
    _Float16* __restrict__ Cout, int M, int N)
{
    constexpr int NT = BN / 16;   // n-tiles per block (4 or 2)
    constexpr int KS = KK / 32;   // k-steps (8 or 16)
    const int tid = threadIdx.x;
    const int w = tid >> 6;
    const int lane = tid & 63;
    const int ln = lane & 15;     // fragment n / m index
    const int lk = lane >> 4;     // fragment k-group
    const int bm = blockIdx.x, bn = blockIdx.y;

    // ---- park B-strip in fragments (AGPR-resident across the k-loop) ----
    f16x8 bf[NT][KS];
#pragma unroll
    for (int c = 0; c < NT; c++) {
        const float* wp = Bw + (long)(bn * BN + c * 16 + ln) * KK + 8 * lk;
#pragma unroll
        for (int kk = 0; kk < KS; kk++) bf[c][kk] = cvt8(wp + kk * 32);
    }

    const long arow = (long)bm * 64 + w * 16 + ln;
    f32x4 acc[NT];
#pragma unroll
    for (int c = 0; c < NT; c++) acc[c] = (f32x4){0.f, 0.f, 0.f, 0.f};

#pragma unroll
    for (int kk = 0; kk < KS; kk++) {
        f16x8 a;
        if (AMODE == 0) {
            a = cvt8(Af32 + arow * KK + kk * 32 + 8 * lk);
        } else if (AMODE == 3) {
            a = *(const f16x8*)(Ah + arow * KK + kk * 32 + 8 * lk);
        } else {  // AMODE == 2: KK=512, halves resolve at compile time per kk
            if (kk < KS / 2)
                a = cvt8(Af32 + arow * 256 + kk * 32 + 8 * lk);
            else
                a = *(const f16x8*)(Ah + arow * 256 + (kk - KS / 2) * 32 + 8 * lk);
        }
#pragma unroll
        for (int c = 0; c < NT; c++)
            acc[c] = __builtin_amdgcn_mfma_f32_16x16x32_f16(a, bf[c][kk], acc[c], 0, 0, 0);
    }

    // ---- epilogue: C row = lk*4 + i, col = ln ----
#pragma unroll
    for (int c = 0; c < NT; c++) {
        const int n = bn * BN + c * 16 + ln;
        const float bi = (EPI == 1) ? bias[n] : 0.f;
#pragma unroll
        for (int i = 0; i < 4; i++) {
            const long m = (long)bm * 64 + w * 16 + lk * 4 + i;
            float v = acc[c][i];
            if (EPI == 1) v += bi;
            if (EPI == 2) v = fast_sigmoid(v) * (float)gateC[m * 256 + n];
            Cout[m * (long)N + n] = (_Float16)v;
        }
    }
}

// ---------------------------------------------------------------------------
// Fused attention: per block = one (p,b) pair (m = p*16+b).
// ---------------------------------------------------------------------------
__global__ __launch_bounds__(256) void attn_k(
    const float* __restrict__ question,  // (Q,B,E) fp32
    const float* __restrict__ vvec,      // (H,) fp32
    const _Float16* __restrict__ Wp,     // (P*B, H) f16
    const _Float16* __restrict__ Wq,     // (Q*B, H) f16
    _Float16* __restrict__ Cc)           // (P*B, E) f16 out
{
    __shared__ float sc[QQ];
    __shared__ float aw[QQ];
    const int tid = threadIdx.x;
    const int blk = blockIdx.x;   // m = p*16 + b
    const int b = blk & 15;
    const int wave = tid >> 6, lane = tid & 63;

    float wp0[4], vv[4];
#pragma unroll
    for (int j = 0; j < 4; j++) {
        wp0[j] = (float)Wp[(long)blk * 256 + lane + 64 * j];
        vv[j] = vvec[lane + 64 * j];
    }
#pragma unroll 2
    for (int qi = 0; qi < 16; qi++) {
        const int q = wave * 16 + qi;
        const _Float16* wqp = Wq + (long)(q * 16 + b) * 256;
        float s = 0.f;
#pragma unroll
        for (int j = 0; j < 4; j++) {
            float x = (float)wqp[lane + 64 * j] + wp0[j];
            s += fast_tanh(x) * vv[j];
        }
#pragma unroll
        for (int off = 32; off; off >>= 1) s += __shfl_xor(s, off, 64);
        if (lane == 0) sc[q] = s;
    }
    __syncthreads();
    if (tid < 64) {
        float s = sc[tid];
        float mx = s;
#pragma unroll
        for (int off = 32; off; off >>= 1) mx = fmaxf(mx, __shfl_xor(mx, off, 64));
        float e = __expf(s - mx);
        float sum = e;
#pragma unroll
        for (int off = 32; off; off >>= 1) sum += __shfl_xor(sum, off, 64);
        aw[tid] = e * __frcp_rn(sum);
    }
    __syncthreads();
    float acc = 0.f;
#pragma unroll 4
    for (int q = 0; q < QQ; q++) {
        acc = fmaf(aw[q], question[(long)(q * 16 + b) * 256 + tid], acc);
    }
    Cc[(long)blk * 256 + tid] = (_Float16)acc;
}

// ---------------------------------------------------------------------------
// GRU scan, v8 = v6 + LDS-only barriers. 16 blocks, 512 threads (8 waves,
// 2/SIMD, 256 unified regs via waves_per_eu(2,2)).
//
// v6 measured 621 us (~2900 cyc/step) with the 2-phase skeleton; a latency
// model of the step says ~1300-1500 cyc. Suspected gap: __syncthreads()
// emits s_waitcnt vmcnt(0) expcnt(0) lgkmcnt(0) before s_barrier (guide,
// m97 analysis), so EVERY step force-drains (a) the 12 gi prefetch loads
// per gate wave (L3/HBM latency 300-900 cyc) and (b) the out stores --
// neither of which the barriers semantically need (they only order LDS:
// gh publish->read, h publish->read). v8 swaps both in-loop barriers for
// lgkmcnt(0)+s_barrier (block_sync_lds); gi loads keep their natural
// counted vmcnt at point of use, out stores are never awaited in-loop.
// ---------------------------------------------------------------------------
__global__ __launch_bounds__(512)
__attribute__((amdgpu_waves_per_eu(2, 2)))
void gru_k(
    const float* __restrict__ whh,    // (768,256) fp32
    const float* __restrict__ bhh,    // (768,) fp32
    const _Float16* __restrict__ gi,  // (P*B, 768) f16 (b_ih folded in)
    float* __restrict__ out)          // (P,B,O) fp32
{
    __shared__ __align__(16) _Float16 hlds[256];   // h broadcast (row 0 of A)
    __shared__ float ghlds[3][256];                // gate pre-activations
    const int tid = threadIdx.x;
    const int w = tid >> 6;        // wave 0..7
    const int lane = tid & 63;
    const int b = blockIdx.x;      // batch

    // ---- stage weights into per-wave B-fragments (AGPR-resident) ----
    f16x8 bf[3][2][8];
#pragma unroll
    for (int g = 0; g < 3; g++)
#pragma unroll
        for (int c = 0; c < 2; c++) {
            const int n0 = g * 256 + 32 * w + 16 * c + (lane & 15);
            const float* wp = whh + (long)n0 * 256 + 8 * (lane >> 4);
#pragma unroll
            for (int kk = 0; kk < 8; kk++) bf[g][c][kk] = cvt8(wp + kk * 32);
        }

    // ---- per-thread state for the epilogue owners (threads 0..255) ----
    float h = 0.f, bhr = 0.f, bhz = 0.f, bhn = 0.f;
    _Float16 gr = (_Float16)0.f, gz = (_Float16)0.f, gn = (_Float16)0.f;
    const _Float16* gip = gi;
    float* outp = out;
    if (tid < 256) {
        hlds[tid] = (_Float16)0.f;
        bhr = bhh[tid]; bhz = bhh[tid + 256]; bhn = bhh[tid + 512];
        gip = gi + (long)b * 768 + tid;
        gr = gip[0]; gz = gip[256]; gn = gip[512];
        outp = out + (long)b * 256 + tid;
    }
    __syncthreads();   // once: drains staging loads + hlds init

    // A-frag source: all lanes in a 16-lane group read the SAME 16B of h
    // (broadcast); non-row-0 lanes mask their copy to zero.
    const unsigned msk = ((lane & 15) == 0) ? 0xFFFFFFFFu : 0u;
    const _Float16* hb = hlds + 8 * (lane >> 4);

    for (int t = 0; t < PP; t++) {
        // Prefetch next step's gi (latency hidden under this step's MFMA;
        // NOT drained at the barriers -- counted vmcnt at use only).
        _Float16 gr2 = (_Float16)0.f, gz2 = (_Float16)0.f, gn2 = (_Float16)0.f;
        if (tid < 256) {
            const _Float16* gq = gip + 16 * 768;
            gr2 = gq[0]; gz2 = gq[256]; gn2 = gq[512];
        }

        // ---- matvec: 48 MFMA per wave ----
        f32x4 a00 = {0.f, 0.f, 0.f, 0.f}, a01 = {0.f, 0.f, 0.f, 0.f};
        f32x4 a10 = {0.f, 0.f, 0.f, 0.f}, a11 = {0.f, 0.f, 0.f, 0.f};
        f32x4 a20 = {0.f, 0.f, 0.f, 0.f}, a21 = {0.f, 0.f, 0.f, 0.f};
#pragma unroll
        for (int kk = 0; kk < 8; kk++) {
            uint4 ra = *(const uint4*)(hb + kk * 32);
            ra.x &= msk; ra.y &= msk; ra.z &= msk; ra.w &= msk;
            f16x8 a = __builtin_bit_cast(f16x8, ra);
            a00 = __builtin_amdgcn_mfma_f32_16x16x32_f16(a, bf[0][0][kk], a00, 0, 0, 0);
            a01 = __builtin_amdgcn_mfma_f32_16x16x32_f16(a, bf[0][1][kk], a01, 0, 0, 0);
            a10 = __builtin_amdgcn_mfma_f32_16x16x32_f16(a, bf[1][0][kk], a10, 0, 0, 0);
            a11 = __builtin_amdgcn_mfma_f32_16x16x32_f16(a, bf[1][1][kk], a11, 0, 0, 0);
            a20 = __builtin_amdgcn_mfma_f32_16x16x32_f16(a, bf[2][0][kk], a20, 0, 0, 0);
            a21 = __builtin_amdgcn_mfma_f32_16x16x32_f16(a, bf[2][1][kk], a21, 0, 0, 0);
        }
        // Row 0 of C lives in lanes 0..15, reg 0 (col = lane&15).
        if (lane < 16) {
            const int e0 = 32 * w + lane;
            ghlds[0][e0] = a00[0]; ghlds[0][e0 + 16] = a01[0];
            ghlds[1][e0] = a10[0]; ghlds[1][e0 + 16] = a11[0];
            ghlds[2][e0] = a20[0]; ghlds[2][e0 + 16] = a21[0];
        }
        block_sync_lds();

        // ---- gates: one e-column per thread, spread over all SIMDs ----
        if (tid < 256) {
            float ghr = ghlds[0][tid] + bhr;
            float ghz = ghlds[1][tid] + bhz;
            float ghn = ghlds[2][tid] + bhn;
            float r = fast_sigmoid((float)gr + ghr);
            float z = fast_sigmoid((float)gz + ghz);
            float n = fast_tanh(fmaf(r, ghn, (float)gn));
            h = (1.f - z) * n + z * h;
            *outp = h;
            hlds[tid] = (_Float16)h;
            gr = gr2; gz = gz2; gn = gn2;
            gip += 16 * 768;
            outp += 16 * 256;
        }
        block_sync_lds();
    }
}

// ---------------------------------------------------------------------------
extern "C" void kernel_launch(void* const* d_in, const int* in_sizes, int n_in,
                              void* d_out, int out_size, void* d_ws, size_t ws_size,
                              hipStream_t stream)
{
    const float* passage  = (const float*)d_in[0];   // (512,16,256) fp32
    const float* question = (const float*)d_in[1];   // (64,16,256) fp32
    const float* Wuq      = (const float*)d_in[2];   // (256,256) fp32
    const float* Wup      = (const float*)d_in[3];   // (256,256) fp32
    const float* vvec     = (const float*)d_in[4];   // (1,256) fp32
    const float* Wg       = (const float*)d_in[5];   // (512,512) fp32
    const float* w_ih     = (const float*)d_in[6];   // (768,256) fp32
    const float* w_hh     = (const float*)d_in[7];   // (768,256) fp32
    const float* b_ih     = (const float*)d_in[8];   // (768,) fp32
    const float* b_hh     = (const float*)d_in[9];   // (768,) fp32

    // Workspace layout (all fp16) — total footprint exactly 16 MiB.
    //   [0,      12.0MiB) : gi (8192x768)  — written LAST; overlaps Wq/Wp/c,
    //                        which are all dead by the time gi is produced.
    //       [0,     0.5MiB) : Wq (1024x256)   dead after attn
    //       [0.5,   4.5MiB) : Wp (8192x256)   dead after attn
    //       [4.5,   8.5MiB) : c  (8192x256)   dead after gate GEMM
    //   [12MiB, 16MiB)     : cg (8192x256)    alive until gi GEMM done
    char* ws = (char*)d_ws;
    _Float16* gi_ws = (_Float16*)(ws);
    _Float16* Wq_ws = (_Float16*)(ws);
    _Float16* Wp_ws = (_Float16*)(ws + (512u << 10));
    _Float16* c_ws  = (_Float16*)(ws + (4608u << 10));
    _Float16* cg_ws = (_Float16*)(ws + (12288u << 10));

    // 1) Wq = question @ Wuq^T   (1024 x 256, K=256)
    gemm_mfma<0, 0, 64, 256><<<dim3(16, 4), 256, 0, stream>>>(
        question, nullptr, Wuq, nullptr, nullptr, Wq_ws, 1024, 256);
    // 2) Wp = passage @ Wup^T    (8192 x 256, K=256)
    gemm_mfma<0, 0, 64, 256><<<dim3(128, 4), 256, 0, stream>>>(
        passage, nullptr, Wup, nullptr, nullptr, Wp_ws, 8192, 256);
    // 3) attention -> c (8192 x 256)
    attn_k<<<8192, 256, 0, stream>>>(question, vvec, Wp_ws, Wq_ws, c_ws);
    // 4) cg = sigmoid([passage,c] @ Wg[256:512]^T) * c   (8192 x 256, K=512)
    gemm_mfma<2, 2, 32, 512><<<dim3(128, 8), 256, 0, stream>>>(
        passage, c_ws, Wg + 256 * 512, nullptr, c_ws, cg_ws, 8192, 256);
    // 5) gi = cg @ w_ih^T + b_ih   (8192 x 768, K=256)
    gemm_mfma<3, 1, 64, 256><<<dim3(128, 12), 256, 0, stream>>>(
        nullptr, cg_ws, w_ih, b_ih, nullptr, gi_ws, 8192, 768);
    // 6) GRU scan -> out (fp32)
    gru_k<<<16, 512, 0, stream>>>(w_hh, b_hh, gi_ws, (float*)d_out);
}

// Round 8
// 883.739 us; speedup vs baseline: 1.3603x; 1.0185x over previous
//
#include <hip/hip_runtime.h>
#include <hip/hip_bf16.h>

// Problem dims
#define PP 512
#define QQ 64
#define BB 16
#define EE 256
#define HH 256
#define OO 256

typedef _Float16 half2_t __attribute__((ext_vector_type(2)));
typedef _Float16 f16x8 __attribute__((ext_vector_type(8)));
typedef float f32x4 __attribute__((ext_vector_type(4)));

__device__ __forceinline__ float fast_tanh(float x) {
    x = fminf(fmaxf(x, -15.f), 15.f);
    float e = __expf(2.f * x);
    return (e - 1.f) * __frcp_rn(e + 1.f);
}
__device__ __forceinline__ float fast_sigmoid(float x) {
    x = fminf(fmaxf(x, -30.f), 30.f);
    return __frcp_rn(1.f + __expf(-x));
}
__device__ __forceinline__ f16x8 cvt8(const float* __restrict__ p) {
    float4 r0 = *(const float4*)(p);
    float4 r1 = *(const float4*)(p + 4);
    f16x8 t;
    t[0] = (_Float16)r0.x; t[1] = (_Float16)r0.y;
    t[2] = (_Float16)r0.z; t[3] = (_Float16)r0.w;
    t[4] = (_Float16)r1.x; t[5] = (_Float16)r1.y;
    t[6] = (_Float16)r1.z; t[7] = (_Float16)r1.w;
    return t;
}
__device__ __forceinline__ float fdot2f(half2_t a, half2_t b, float c) {
#if defined(__has_builtin)
#if __has_builtin(__builtin_amdgcn_fdot2)
    return __builtin_amdgcn_fdot2(a, b, c, false);
#else
    return (float)a[0] * (float)b[0] + (float)a[1] * (float)b[1] + c;
#endif
#else
    return (float)a[0] * (float)b[0] + (float)a[1] * (float)b[1] + c;
#endif
}

// LDS-only barrier: orders ds_write -> barrier -> ds_read WITHOUT the
// vmcnt(0)/expcnt(0) drain __syncthreads() emits. (Measured r7: no perf
// delta vs __syncthreads on the MFMA scan, but semantically safe and free;
// kept so per-step global ops are never drained.)
__device__ __forceinline__ void block_sync_lds() {
    __builtin_amdgcn_sched_barrier(0);
    asm volatile("s_waitcnt lgkmcnt(0)" ::: "memory");
    __builtin_amdgcn_s_barrier();
    __builtin_amdgcn_sched_barrier(0);
}

// ---------------------------------------------------------------------------
// MFMA GEMM with register-resident B: C[m,n] = epi( sum_k A[m,k]*B[n,k] ).
// (unchanged from round 6 -- verified, ~all four dispatches sum ~200us)
// ---------------------------------------------------------------------------
template <int AMODE, int EPI, int BN, int KK>
__global__ __launch_bounds__(256)
__attribute__((amdgpu_waves_per_eu(2, 2)))
void gemm_mfma(
    const float* __restrict__ Af32,
    const _Float16* __restrict__ Ah,
    const float* __restrict__ Bw,
    const float* __restrict__ bias,
    const _Float16* __restrict__ gateC,
    _Float16* __restrict__ Cout, int M, int N)
{
    constexpr int NT = BN / 16;   // n-tiles per block (4 or 2)
    constexpr int KS = KK / 32;   // k-steps (8 or 16)
    const int tid = threadIdx.x;
    const int w = tid >> 6;
    const int lane = tid & 63;
    const int ln = lane & 15;     // fragment n / m index
    const int lk = lane >> 4;     // fragment k-group
    const int bm = blockIdx.x, bn = blockIdx.y;

    // ---- park B-strip in fragments (AGPR-resident across the k-loop) ----
    f16x8 bf[NT][KS];
#pragma unroll
    for (int c = 0; c < NT; c++) {
        const float* wp = Bw + (long)(bn * BN + c * 16 + ln) * KK + 8 * lk;
#pragma unroll
        for (int kk = 0; kk < KS; kk++) bf[c][kk] = cvt8(wp + kk * 32);
    }

    const long arow = (long)bm * 64 + w * 16 + ln;
    f32x4 acc[NT];
#pragma unroll
    for (int c = 0; c < NT; c++) acc[c] = (f32x4){0.f, 0.f, 0.f, 0.f};

#pragma unroll
    for (int kk = 0; kk < KS; kk++) {
        f16x8 a;
        if (AMODE == 0) {
            a = cvt8(Af32 + arow * KK + kk * 32 + 8 * lk);
        } else if (AMODE == 3) {
            a = *(const f16x8*)(Ah + arow * KK + kk * 32 + 8 * lk);
        } else {  // AMODE == 2: KK=512, halves resolve at compile time per kk
            if (kk < KS / 2)
                a = cvt8(Af32 + arow * 256 + kk * 32 + 8 * lk);
            else
                a = *(const f16x8*)(Ah + arow * 256 + (kk - KS / 2) * 32 + 8 * lk);
        }
#pragma unroll
        for (int c = 0; c < NT; c++)
            acc[c] = __builtin_amdgcn_mfma_f32_16x16x32_f16(a, bf[c][kk], acc[c], 0, 0, 0);
    }

    // ---- epilogue: C row = lk*4 + i, col = ln ----
#pragma unroll
    for (int c = 0; c < NT; c++) {
        const int n = bn * BN + c * 16 + ln;
        const float bi = (EPI == 1) ? bias[n] : 0.f;
#pragma unroll
        for (int i = 0; i < 4; i++) {
            const long m = (long)bm * 64 + w * 16 + lk * 4 + i;
            float v = acc[c][i];
            if (EPI == 1) v += bi;
            if (EPI == 2) v = fast_sigmoid(v) * (float)gateC[m * 256 + n];
            Cout[m * (long)N + n] = (_Float16)v;
        }
    }
}

// ---------------------------------------------------------------------------
// Fused attention: per block = one (p,b) pair (m = p*16+b).  (unchanged)
// ---------------------------------------------------------------------------
__global__ __launch_bounds__(256) void attn_k(
    const float* __restrict__ question,  // (Q,B,E) fp32
    const float* __restrict__ vvec,      // (H,) fp32
    const _Float16* __restrict__ Wp,     // (P*B, H) f16
    const _Float16* __restrict__ Wq,     // (Q*B, H) f16
    _Float16* __restrict__ Cc)           // (P*B, E) f16 out
{
    __shared__ float sc[QQ];
    __shared__ float aw[QQ];
    const int tid = threadIdx.x;
    const int blk = blockIdx.x;   // m = p*16 + b
    const int b = blk & 15;
    const int wave = tid >> 6, lane = tid & 63;

    float wp0[4], vv[4];
#pragma unroll
    for (int j = 0; j < 4; j++) {
        wp0[j] = (float)Wp[(long)blk * 256 + lane + 64 * j];
        vv[j] = vvec[lane + 64 * j];
    }
#pragma unroll 2
    for (int qi = 0; qi < 16; qi++) {
        const int q = wave * 16 + qi;
        const _Float16* wqp = Wq + (long)(q * 16 + b) * 256;
        float s = 0.f;
#pragma unroll
        for (int j = 0; j < 4; j++) {
            float x = (float)wqp[lane + 64 * j] + wp0[j];
            s += fast_tanh(x) * vv[j];
        }
#pragma unroll
        for (int off = 32; off; off >>= 1) s += __shfl_xor(s, off, 64);
        if (lane == 0) sc[q] = s;
    }
    __syncthreads();
    if (tid < 64) {
        float s = sc[tid];
        float mx = s;
#pragma unroll
        for (int off = 32; off; off >>= 1) mx = fmaxf(mx, __shfl_xor(mx, off, 64));
        float e = __expf(s - mx);
        float sum = e;
#pragma unroll
        for (int off = 32; off; off >>= 1) sum += __shfl_xor(sum, off, 64);
        aw[tid] = e * __frcp_rn(sum);
    }
    __syncthreads();
    float acc = 0.f;
#pragma unroll 4
    for (int q = 0; q < QQ; q++) {
        acc = fmaf(aw[q], question[(long)(q * 16 + b) * 256 + tid], acc);
    }
    Cc[(long)blk * 256 + tid] = (_Float16)acc;
}

// ---------------------------------------------------------------------------
// GRU scan, v10: dot2 matvec at 256-reg budget. 16 blocks (one per batch),
// 512 threads (8 waves, 2/SIMD via waves_per_eu(2,2) -> 256 unified regs).
//
// r7 re-derivation: the 16x16x32 MFMA is ~16 cyc per SIMD (the 4.85-cyc
// ubench figure is per-CU over 4 SIMDs); counters confirm (MfmaUtil 52% on
// active CUs = 1516 of 2915 cyc/step). M=1-of-16 waste makes the MFMA
// decomposition's floor ~1776 cyc/step, and per-block MFMA count is
// independent of M, so no batching fixes it. The VALU decomposition's floor
// is 768 cyc/SIMD/step (192 wave-dot2 x 2cyc x 2 waves) -- HALF the MFMA
// floor. Rounds 0-3 lost this path only to the register allocator at
// budget <=128 regs/wave. Here: 2-way K-split -> 192 weight half2 + ~40
// working ~= 232 regs, inside the 256 budget at 2 waves/SIMD. Even if the
// allocator grants only 128 arch (64 half2 AGPR-taxed at +256 cyc/SIMD),
// the model still beats the measured 622us MFMA scan in every branch.
// Thread (q,e): q=K-half, e=output element; q==0 threads (waves 0-3, one
// per SIMD) own the gate epilogue. Gate math identical to v5 (passed).
// ---------------------------------------------------------------------------
__global__ __launch_bounds__(512)
__attribute__((amdgpu_waves_per_eu(2, 2), amdgpu_num_vgpr(256)))
void gru_k(
    const float* __restrict__ whh,    // (768,256) fp32
    const float* __restrict__ bhh,    // (768,) fp32
    const _Float16* __restrict__ gi,  // (P*B, 768) f16 (b_ih folded in)
    float* __restrict__ out)          // (P,B,O) fp32
{
    __shared__ __align__(16) _Float16 hbuf[2][256];   // h broadcast, dbuf
    __shared__ float part[3][256];                    // q=1 partials
    const int tid = threadIdx.x;
    const int q = tid >> 8;       // K-half 0/1
    const int e = tid & 255;
    const int b = blockIdx.x;
    const int koff = q * 128;

    // Weight slices: rows e (r), e+256 (z), e+512 (n), cols [koff, koff+128)
    // = 64 half2 per gate = 192 half2 total, held in registers for the scan.
    half2_t wr[64], wz[64], wn[64];
    {
        const float* pr = whh + (long)e * 256 + koff;
        const float* pz = whh + (long)(e + 256) * 256 + koff;
        const float* pn = whh + (long)(e + 512) * 256 + koff;
#pragma unroll
        for (int j = 0; j < 32; j++) {
            float4 a = *(const float4*)(pr + 4 * j);
            float4 c = *(const float4*)(pz + 4 * j);
            float4 d = *(const float4*)(pn + 4 * j);
            half2_t t;
            t[0] = (_Float16)a.x; t[1] = (_Float16)a.y; wr[2 * j] = t;
            t[0] = (_Float16)a.z; t[1] = (_Float16)a.w; wr[2 * j + 1] = t;
            t[0] = (_Float16)c.x; t[1] = (_Float16)c.y; wz[2 * j] = t;
            t[0] = (_Float16)c.z; t[1] = (_Float16)c.w; wz[2 * j + 1] = t;
            t[0] = (_Float16)d.x; t[1] = (_Float16)d.y; wn[2 * j] = t;
            t[0] = (_Float16)d.z; t[1] = (_Float16)d.w; wn[2 * j + 1] = t;
        }
    }
    float b_r = 0.f, b_z = 0.f, b_n = 0.f;
    _Float16 gr = (_Float16)0.f, gz = (_Float16)0.f, gn = (_Float16)0.f;
    const _Float16* gip = gi;
    float* outp = out;
    if (q == 0) {
        b_r = bhh[e];
        b_z = bhh[e + 256];
        b_n = bhh[e + 512];
        hbuf[0][e] = (_Float16)0.f;
        gip = gi + (long)b * 768 + e;
        gr = gip[0]; gz = gip[256]; gn = gip[512];   // step-0 gi
        outp = out + (long)b * 256 + e;
    }
    float h = 0.f;
    __syncthreads();

    int cur = 0;
    for (int t = 0; t < PP; t++) {
        // Prefetch NEXT step's gi (consumed after the next barrier pair;
        // ~2 matvec phases of slack cover HBM latency). t=511 reads one row
        // past gi -- inside the 16 MiB workspace, value unused.
        _Float16 gr2 = (_Float16)0.f, gz2 = (_Float16)0.f, gn2 = (_Float16)0.f;
        if (q == 0) {
            const _Float16* gq = gip + 16 * 768;
            gr2 = gq[0]; gz2 = gq[256]; gn2 = gq[512];
        }
        // Half-dot over this thread's 128-wide k-slice of the broadcast h.
        // hp4 is wave-uniform (depends only on q) -> same-address broadcast
        // reads, conflict-free.
        const uint4* hp4 = ((const uint4*)hbuf[cur]) + q * 16;
        float ar = 0.f, az = 0.f, an = 0.f;
#pragma unroll
        for (int j = 0; j < 16; j++) {
            uint4 hp = hp4[j];
            half2_t h0 = __builtin_bit_cast(half2_t, hp.x);
            half2_t h1 = __builtin_bit_cast(half2_t, hp.y);
            half2_t h2 = __builtin_bit_cast(half2_t, hp.z);
            half2_t h3 = __builtin_bit_cast(half2_t, hp.w);
            ar = fdot2f(wr[4 * j + 0], h0, ar);
            ar = fdot2f(wr[4 * j + 1], h1, ar);
            ar = fdot2f(wr[4 * j + 2], h2, ar);
            ar = fdot2f(wr[4 * j + 3], h3, ar);
            az = fdot2f(wz[4 * j + 0], h0, az);
            az = fdot2f(wz[4 * j + 1], h1, az);
            az = fdot2f(wz[4 * j + 2], h2, az);
            az = fdot2f(wz[4 * j + 3], h3, az);
            an = fdot2f(wn[4 * j + 0], h0, an);
            an = fdot2f(wn[4 * j + 1], h1, an);
            an = fdot2f(wn[4 * j + 2], h2, an);
            an = fdot2f(wn[4 * j + 3], h3, an);
        }
        if (q) {
            part[0][e] = ar;
            part[1][e] = az;
            part[2][e] = an;
        }
        block_sync_lds();
        if (q == 0) {
            float ghr = ar + part[0][e] + b_r;
            float ghz = az + part[1][e] + b_z;
            float ghn = an + part[2][e] + b_n;
            float r = fast_sigmoid((float)gr + ghr);
            float z = fast_sigmoid((float)gz + ghz);
            float n = fast_tanh(fmaf(r, ghn, (float)gn));
            h = (1.f - z) * n + z * h;
            *outp = h;
            hbuf[cur ^ 1][e] = (_Float16)h;
            gr = gr2; gz = gz2; gn = gn2;
            gip += 16 * 768;
            outp += 16 * 256;
        }
        block_sync_lds();
        cur ^= 1;
    }
}

// ---------------------------------------------------------------------------
extern "C" void kernel_launch(void* const* d_in, const int* in_sizes, int n_in,
                              void* d_out, int out_size, void* d_ws, size_t ws_size,
                              hipStream_t stream)
{
    const float* passage  = (const float*)d_in[0];   // (512,16,256) fp32
    const float* question = (const float*)d_in[1];   // (64,16,256) fp32
    const float* Wuq      = (const float*)d_in[2];   // (256,256) fp32
    const float* Wup      = (const float*)d_in[3];   // (256,256) fp32
    const float* vvec     = (const float*)d_in[4];   // (1,256) fp32
    const float* Wg       = (const float*)d_in[5];   // (512,512) fp32
    const float* w_ih     = (const float*)d_in[6];   // (768,256) fp32
    const float* w_hh     = (const float*)d_in[7];   // (768,256) fp32
    const float* b_ih     = (const float*)d_in[8];   // (768,) fp32
    const float* b_hh     = (const float*)d_in[9];   // (768,) fp32

    // Workspace layout (all fp16) — total footprint exactly 16 MiB.
    //   [0,      12.0MiB) : gi (8192x768)  — written LAST; overlaps Wq/Wp/c,
    //                        which are all dead by the time gi is produced.
    //       [0,     0.5MiB) : Wq (1024x256)   dead after attn
    //       [0.5,   4.5MiB) : Wp (8192x256)   dead after attn
    //       [4.5,   8.5MiB) : c  (8192x256)   dead after gate GEMM
    //   [12MiB, 16MiB)     : cg (8192x256)    alive until gi GEMM done
    char* ws = (char*)d_ws;
    _Float16* gi_ws = (_Float16*)(ws);
    _Float16* Wq_ws = (_Float16*)(ws);
    _Float16* Wp_ws = (_Float16*)(ws + (512u << 10));
    _Float16* c_ws  = (_Float16*)(ws + (4608u << 10));
    _Float16* cg_ws = (_Float16*)(ws + (12288u << 10));

    // 1) Wq = question @ Wuq^T   (1024 x 256, K=256)
    gemm_mfma<0, 0, 64, 256><<<dim3(16, 4), 256, 0, stream>>>(
        question, nullptr, Wuq, nullptr, nullptr, Wq_ws, 1024, 256);
    // 2) Wp = passage @ Wup^T    (8192 x 256, K=256)
    gemm_mfma<0, 0, 64, 256><<<dim3(128, 4), 256, 0, stream>>>(
        passage, nullptr, Wup, nullptr, nullptr, Wp_ws, 8192, 256);
    // 3) attention -> c (8192 x 256)
    attn_k<<<8192, 256, 0, stream>>>(question, vvec, Wp_ws, Wq_ws, c_ws);
    // 4) cg = sigmoid([passage,c] @ Wg[256:512]^T) * c   (8192 x 256, K=512)
    gemm_mfma<2, 2, 32, 512><<<dim3(128, 8), 256, 0, stream>>>(
        passage, c_ws, Wg + 256 * 512, nullptr, c_ws, cg_ws, 8192, 256);
    // 5) gi = cg @ w_ih^T + b_ih   (8192 x 768, K=256)
    gemm_mfma<3, 1, 64, 256><<<dim3(128, 12), 256, 0, stream>>>(
        nullptr, cg_ws, w_ih, b_ih, nullptr, gi_ws, 8192, 768);
    // 6) GRU scan -> out (fp32)
    gru_k<<<16, 512, 0, stream>>>(w_hh, b_hh, gi_ws, (float*)d_out);
}